// Round 8
// baseline (146.120 us; speedup 1.0000x reference)
//
#include <hip/hip_runtime.h>
#include <hip/hip_cooperative_groups.h>
#include <hip/hip_bf16.h>
#include <cstdint>

namespace cg = cooperative_groups;

// Problem constants (ConceptBoxModel): B=256, L=512, N=64, D=32, C=100
constexpr int Bb = 256, Ll = 512, Nn = 64, Dd = 32, Cc = 100;
constexpr float EPS = 1e-6f;

typedef __attribute__((ext_vector_type(8))) short short8;   // 8 bf16
typedef __attribute__((ext_vector_type(4))) float f32x4;    // MFMA C/D frag

__device__ __forceinline__ unsigned short f2bf(float f) {
  union { float f; uint32_t u; } v; v.f = f;
  uint32_t r = v.u + 0x7FFFu + ((v.u >> 16) & 1u);   // RNE
  return (unsigned short)(r >> 16);
}

// one LDS arena shared across phases (max = phase C1: 50 KB)
union USm {
  struct {                                  // phase A (MFMA kA)
    unsigned short hb[64][64];              // [row][k] bf16
    unsigned short wbT[64][72];             // [col][k] bf16 (pad 72)
  } a;
  struct {                                  // phase B
    float lo[64][36];
    float hi[64][36];
    float rvol[64];
  } b;
  struct {                                  // phase C1
    float Wt[64][132];                      // [kk][col]
    float At[64][68];                       // [kk][row]
  } c;
};

// ---------------------------------------------------------------------------
// Fused kernel: 256 blocks x 256 threads, cooperative (grid.sync between
// phases).  Phase A: MFMA projections; B: pairwise volumes; C1: split-K
// GEMM partials; C2: reduce.
// ---------------------------------------------------------------------------
__global__ __launch_bounds__(256) void fused(
    const float* __restrict__ h,    // [256][512]
    const float* __restrict__ Wc,   // [64][512][32]
    const float* __restrict__ bc,   // [64][32]
    const float* __restrict__ Wo,
    const float* __restrict__ bo,
    const float* __restrict__ Wp,   // [64][64]
    const float* __restrict__ bp,   // [64]
    const float* __restrict__ W1,   // [4096][100]
    const float* __restrict__ b1,
    const float* __restrict__ W2,   // [4096][100]
    const float* __restrict__ b2,
    float* __restrict__ xm_ws,      // [256][64][32]
    float* __restrict__ dl_ws,      // [256][64][32]
    float* __restrict__ ph_ws,      // [256][64]
    float* __restrict__ part,       // [64][256][100]
    float* __restrict__ out_y,      // [256][100]
    float* __restrict__ out_ph,     // [256][64]
    float* __restrict__ out_V)      // [256][64][64]
{
  __shared__ USm u;
  cg::grid_group grid = cg::this_grid();
  const int bid = blockIdx.x;
  const int t   = threadIdx.x;

  // ============================ Phase A ==================================
  // x_m = h@Wc + bc ; delta = softplus(h@Wo + bo) ; p_hat.
  // block: n = bid&63, 64 b-rows; wave w rows w*16..+15; 8 MFMA/chunk.
  {
    const int n  = bid & 63;
    const int bt = (bid >> 6) * 64;
    const int w  = t >> 6, l = t & 63;
    const int lr = l & 15, lg = l >> 4;

    f32x4 acc[4] = {};   // nf 0,1 -> xm cols; nf 2,3 -> dl cols

    const int hr = t >> 2,       hc  = (t & 3) * 16;   // h staging
    const int wk = (t >> 3) * 2, wcq = (t & 7) * 4;    // W staging
    const float* hsrc  = h  + (bt + hr) * Ll + hc;
    const float* wcsrc = Wc + n * (Ll * Dd) + wk * Dd + wcq;
    const float* wosrc = Wo + n * (Ll * Dd) + wk * Dd + wcq;

    float4 hp0, hp1, hp2, hp3, c0, c1, o0, o1;
    auto fetch = [&](int k0) {
      const float* hs = hsrc + k0;
      hp0 = *(const float4*)(hs);
      hp1 = *(const float4*)(hs + 4);
      hp2 = *(const float4*)(hs + 8);
      hp3 = *(const float4*)(hs + 12);
      const float* ws = wcsrc + k0 * Dd;
      c0 = *(const float4*)(ws);
      c1 = *(const float4*)(ws + Dd);
      const float* os = wosrc + k0 * Dd;
      o0 = *(const float4*)(os);
      o1 = *(const float4*)(os + Dd);
    };

    fetch(0);
    for (int ch = 0; ch < 8; ch++) {
      __syncthreads();
      {
        unsigned short* hd = &u.a.hb[hr][hc];
        hd[0]  = f2bf(hp0.x); hd[1]  = f2bf(hp0.y);
        hd[2]  = f2bf(hp0.z); hd[3]  = f2bf(hp0.w);
        hd[4]  = f2bf(hp1.x); hd[5]  = f2bf(hp1.y);
        hd[6]  = f2bf(hp1.z); hd[7]  = f2bf(hp1.w);
        hd[8]  = f2bf(hp2.x); hd[9]  = f2bf(hp2.y);
        hd[10] = f2bf(hp2.z); hd[11] = f2bf(hp2.w);
        hd[12] = f2bf(hp3.x); hd[13] = f2bf(hp3.y);
        hd[14] = f2bf(hp3.z); hd[15] = f2bf(hp3.w);
      }
      {
        const float* c0p = &c0.x; const float* c1p = &c1.x;
        const float* o0p = &o0.x; const float* o1p = &o1.x;
        #pragma unroll
        for (int i = 0; i < 4; i++) {
          unsigned int pc = (unsigned int)f2bf(c0p[i]) |
                            ((unsigned int)f2bf(c1p[i]) << 16);
          *(unsigned int*)&u.a.wbT[wcq + i][wk] = pc;
          unsigned int po = (unsigned int)f2bf(o0p[i]) |
                            ((unsigned int)f2bf(o1p[i]) << 16);
          *(unsigned int*)&u.a.wbT[32 + wcq + i][wk] = po;
        }
      }
      __syncthreads();
      if (ch < 7) fetch((ch + 1) * 64);
      const int arow = w * 16 + lr;
      #pragma unroll
      for (int ks = 0; ks < 2; ks++) {
        const int ko = ks * 32 + lg * 8;
        const short8 av = *(const short8*)&u.a.hb[arow][ko];
        #pragma unroll
        for (int nf = 0; nf < 4; nf++) {
          const short8 bv = *(const short8*)&u.a.wbT[nf * 16 + lr][ko];
          acc[nf] = __builtin_amdgcn_mfma_f32_16x16x32_bf16(av, bv, acc[nf],
                                                            0, 0, 0);
        }
      }
    }

    const float bc0 = bc[n * Dd + lr],      bc1 = bc[n * Dd + 16 + lr];
    const float bo0 = bo[n * Dd + lr],      bo1 = bo[n * Dd + 16 + lr];
    const float wp0 = Wp[n * 64 + lr],      wp1 = Wp[n * 64 + 16 + lr];
    const float wp2 = Wp[n * 64 + 32 + lr], wp3 = Wp[n * 64 + 48 + lr];
    const float bpv = bp[n];

    #pragma unroll
    for (int q = 0; q < 4; q++) {
      const int b = bt + w * 16 + lg * 4 + q;
      const float xm0  = acc[0][q] + bc0;
      const float xm1  = acc[1][q] + bc1;
      const float pre0 = acc[2][q] + bo0;
      const float pre1 = acc[3][q] + bo1;
      const float dl0 = fmaxf(pre0, 0.f) + log1pf(expf(-fabsf(pre0)));
      const float dl1 = fmaxf(pre1, 0.f) + log1pf(expf(-fabsf(pre1)));
      float* xp = xm_ws + b * 2048 + n * Dd;
      float* dp = dl_ws + b * 2048 + n * Dd;
      xp[lr] = xm0;  xp[16 + lr] = xm1;
      dp[lr] = dl0;  dp[16 + lr] = dl1;
      float pp = xm0 * wp0 + xm1 * wp1 + dl0 * wp2 + dl1 * wp3;
      pp += __shfl_xor(pp, 1);
      pp += __shfl_xor(pp, 2);
      pp += __shfl_xor(pp, 4);
      pp += __shfl_xor(pp, 8);
      if (lr == 0) {
        const float ph = 1.f / (1.f + expf(-(pp + bpv)));
        ph_ws[b * 64 + n] = ph;
        out_ph[b * 64 + n] = ph;
      }
    }
  }
  grid.sync();

  // ============================ Phase B ==================================
  // pairwise intersection volumes V[b,i,j], one block per b.
  {
    const int b = bid;
    {
      const int n = t >> 2, dd = (t & 3) * 8;
      const float* xp = xm_ws + b * 2048 + n * Dd + dd;
      const float* dp = dl_ws + b * 2048 + n * Dd + dd;
      #pragma unroll
      for (int i = 0; i < 8; i += 4) {
        float4 x = *(const float4*)(xp + i);
        float4 g = *(const float4*)(dp + i);
        u.b.lo[n][dd + i + 0] = x.x - g.x;  u.b.hi[n][dd + i + 0] = x.x + g.x;
        u.b.lo[n][dd + i + 1] = x.y - g.y;  u.b.hi[n][dd + i + 1] = x.y + g.y;
        u.b.lo[n][dd + i + 2] = x.z - g.z;  u.b.hi[n][dd + i + 2] = x.z + g.z;
        u.b.lo[n][dd + i + 3] = x.w - g.w;  u.b.hi[n][dd + i + 3] = x.w + g.w;
      }
    }
    if (t < 64) {
      const float* dp = dl_ws + b * 2048 + t * Dd;
      float p = 1.f;
      #pragma unroll
      for (int dd = 0; dd < 32; dd++) p *= dp[dd] + EPS;
      u.b.rvol[t] = 1.f / p;
    }
    __syncthreads();

    const int i0 = t >> 6;
    const int j  = t & 63;
    #pragma unroll 1
    for (int it = 0; it < 16; it++) {
      const int i = i0 + 4 * it;
      float prod = 1.f;
      #pragma unroll
      for (int dd = 0; dd < 32; dd += 4) {
        float4 hj = *(const float4*)&u.b.hi[j][dd];
        float4 lj = *(const float4*)&u.b.lo[j][dd];
        float4 hv = *(const float4*)&u.b.hi[i][dd];
        float4 lv = *(const float4*)&u.b.lo[i][dd];
        float v0 = fmaxf(fminf(hv.x,hj.x)-fmaxf(lv.x,lj.x),0.f)*0.5f + EPS;
        float v1 = fmaxf(fminf(hv.y,hj.y)-fmaxf(lv.y,lj.y),0.f)*0.5f + EPS;
        float v2 = fmaxf(fminf(hv.z,hj.z)-fmaxf(lv.z,lj.z),0.f)*0.5f + EPS;
        float v3 = fmaxf(fminf(hv.w,hj.w)-fmaxf(lv.w,lj.w),0.f)*0.5f + EPS;
        prod *= v0 * v1 * v2 * v3;
      }
      out_V[b * 4096 + i * 64 + j] = prod * u.b.rvol[j];
    }
    __syncthreads();   // LDS arena about to be reused
  }
  grid.sync();

  // ============================ Phase C1 =================================
  // split-K GEMM partials: A=[aligned|V] [256][8192] @ [W1;W2] [8192][100].
  // bg = bid&3 (64 rows), s = bid>>2 (64 slices, KSL=128, 2 chunks of 64).
  {
    const int bg = bid & 3;
    const int s  = bid >> 2;
    const bool isV = (s >= 32);
    const int m0 = (s & 31) * 128;
    const float* __restrict__ W = isV ? W2 : W1;

    const int tx = t & 15;          // col quads tx, tx+16
    const int ty = t >> 4;          // rows ty*4..+3

    float acc[4][8] = {};

    const int wrw = t >> 2, wq8 = (t & 3) * 8;   // W staging: row, quad base
    const int arow = t >> 2, aq = t & 3;         // A staging: row, octet base
    const int brow_s = bg * 64 + arow;

    float4 wreg[8];
    float4 areg[2][2];
    auto load_chunk = [&](int mbase) {
      const float* wr = W + (mbase + wrw) * Cc;
      #pragma unroll
      for (int j = 0; j < 8; j++) {
        const int c = (wq8 + j) * 4;
        wreg[j] = (c < Cc) ? *(const float4*)(wr + c)
                           : make_float4(0.f, 0.f, 0.f, 0.f);
      }
      #pragma unroll
      for (int p = 0; p < 2; p++) {
        const int mk = mbase + (aq + p * 4) * 8;
        if (!isV) {
          const int nn = mk >> 6, sub = mk & 63;
          const float phv = ph_ws[brow_s * 64 + nn];
          const float* src = (sub < 32)
              ? (xm_ws + brow_s * 2048 + nn * Dd + sub)
              : (dl_ws + brow_s * 2048 + nn * Dd + (sub - 32));
          float4 v0 = *(const float4*)(src);
          float4 v1 = *(const float4*)(src + 4);
          v0.x *= phv; v0.y *= phv; v0.z *= phv; v0.w *= phv;
          v1.x *= phv; v1.y *= phv; v1.z *= phv; v1.w *= phv;
          areg[p][0] = v0; areg[p][1] = v1;
        } else {
          const float* src = out_V + brow_s * 4096 + mk;
          areg[p][0] = *(const float4*)(src);
          areg[p][1] = *(const float4*)(src + 4);
        }
      }
    };

    load_chunk(m0);
    for (int ch = 0; ch < 2; ch++) {
      __syncthreads();
      #pragma unroll
      for (int j = 0; j < 8; j++) {
        const int c = (wq8 + j) * 4;
        if (c < Cc) *(float4*)&u.c.Wt[wrw][c] = wreg[j];
      }
      #pragma unroll
      for (int p = 0; p < 2; p++) {
        const int k8 = (aq + p * 4) * 8;
        u.c.At[k8 + 0][arow] = areg[p][0].x;
        u.c.At[k8 + 1][arow] = areg[p][0].y;
        u.c.At[k8 + 2][arow] = areg[p][0].z;
        u.c.At[k8 + 3][arow] = areg[p][0].w;
        u.c.At[k8 + 4][arow] = areg[p][1].x;
        u.c.At[k8 + 5][arow] = areg[p][1].y;
        u.c.At[k8 + 6][arow] = areg[p][1].z;
        u.c.At[k8 + 7][arow] = areg[p][1].w;
      }
      __syncthreads();
      if (ch == 0) load_chunk(m0 + 64);
      #pragma unroll 4
      for (int kk = 0; kk < 64; kk++) {
        const float4 a4  = *(const float4*)&u.c.At[kk][ty * 4];
        const float4 wlo = *(const float4*)&u.c.Wt[kk][tx * 4];
        const float4 whi = *(const float4*)&u.c.Wt[kk][(tx + 16) * 4];
        const float* ap = &a4.x;
        #pragma unroll
        for (int r = 0; r < 4; r++) {
          const float av = ap[r];
          acc[r][0] += av * wlo.x; acc[r][1] += av * wlo.y;
          acc[r][2] += av * wlo.z; acc[r][3] += av * wlo.w;
          acc[r][4] += av * whi.x; acc[r][5] += av * whi.y;
          acc[r][6] += av * whi.z; acc[r][7] += av * whi.w;
        }
      }
    }

    #pragma unroll
    for (int r = 0; r < 4; r++) {
      const int brow = bg * 64 + ty * 4 + r;
      float* pr = part + (s * 256 + brow) * Cc;
      #pragma unroll
      for (int q = 0; q < 2; q++) {
        const int c0 = (tx + q * 16) * 4;
        if (c0 < Cc) {
          pr[c0 + 0] = acc[r][q * 4 + 0];
          pr[c0 + 1] = acc[r][q * 4 + 1];
          pr[c0 + 2] = acc[r][q * 4 + 2];
          pr[c0 + 3] = acc[r][q * 4 + 3];
        }
      }
    }
  }
  grid.sync();

  // ============================ Phase C2 =================================
  // reduce 64 partials + biases -> y.
  {
    const int o = bid * 256 + t;
    if (o < Bb * Cc) {
      const int c = o % Cc;
      float sum = b1[c] + b2[c];
      #pragma unroll 8
      for (int sl = 0; sl < 64; sl++) sum += part[sl * (Bb * Cc) + o];
      out_y[o] = sum;
    }
  }
}

// ---------------------------------------------------------------------------
extern "C" void kernel_launch(void* const* d_in, const int* in_sizes, int n_in,
                              void* d_out, int out_size, void* d_ws, size_t ws_size,
                              hipStream_t stream) {
  const float* h  = (const float*)d_in[0];
  const float* Wc = (const float*)d_in[1];
  const float* bc = (const float*)d_in[2];
  const float* Wo = (const float*)d_in[3];
  const float* bo = (const float*)d_in[4];
  const float* Wp = (const float*)d_in[5];
  const float* bp = (const float*)d_in[6];
  const float* W1 = (const float*)d_in[7];
  const float* b1 = (const float*)d_in[8];
  const float* W2 = (const float*)d_in[9];
  const float* b2 = (const float*)d_in[10];

  float* out    = (float*)d_out;
  float* out_y  = out;                         // [256][100]
  float* out_ph = out + Bb * Cc;               // [256][64]
  float* out_V  = out + Bb * Cc + Bb * Nn;     // [256][64][64]

  float* xm   = (float*)d_ws;              // 524288 f32 (2 MB)
  float* dl   = xm + Bb * Nn * Dd;         // 524288 f32 (2 MB)
  float* ph   = dl + Bb * Nn * Dd;         // 16384 f32
  float* part = ph + Bb * Nn;              // 64*25600 f32 (6.55 MB)

  void* args[] = {
    (void*)&h,  (void*)&Wc, (void*)&bc, (void*)&Wo, (void*)&bo,
    (void*)&Wp, (void*)&bp, (void*)&W1, (void*)&b1, (void*)&W2, (void*)&b2,
    (void*)&xm, (void*)&dl, (void*)&ph, (void*)&part,
    (void*)&out_y, (void*)&out_ph, (void*)&out_V
  };
  hipLaunchCooperativeKernel((const void*)fused, dim3(256), dim3(256),
                             args, 0, stream);
}

// Round 9
// 51.453 us; speedup vs baseline: 2.8399x; 2.8399x over previous
//
#include <hip/hip_runtime.h>
#include <hip/hip_bf16.h>
#include <cstdint>

// Problem constants (ConceptBoxModel): B=256, L=512, N=64, D=32, C=100
constexpr int Bb = 256, Ll = 512, Nn = 64, Dd = 32, Cc = 100;
constexpr float EPS = 1e-6f;

typedef __attribute__((ext_vector_type(8))) short short8;   // 8 bf16
typedef __attribute__((ext_vector_type(4))) float f32x4;    // MFMA C/D frag

__device__ __forceinline__ unsigned short f2bf(float f) {
  union { float f; uint32_t u; } v; v.f = f;
  uint32_t r = v.u + 0x7FFFu + ((v.u >> 16) & 1u);   // RNE
  return (unsigned short)(r >> 16);
}

// ---------------------------------------------------------------------------
// Kernel A v6 (MFMA): x_m = h@Wc + bc ; delta = softplus(h@Wo + bo) ; p_hat
// grid (n=64 fast, bt=4) = 256 blocks x 256 thr.  hb padded to 72 shorts/row
// (144B): staging u16 stores 2-way (free), b128 frag reads at bank floor.
// ---------------------------------------------------------------------------
__global__ __launch_bounds__(256) void kA(
    const float* __restrict__ h,    // [256][512]
    const float* __restrict__ Wc,   // [64][512][32]
    const float* __restrict__ bc,   // [64][32]
    const float* __restrict__ Wo,
    const float* __restrict__ bo,
    const float* __restrict__ Wp,   // [64][64]
    const float* __restrict__ bp,   // [64]
    float* __restrict__ xm_ws,      // [256][64][32]
    float* __restrict__ dl_ws,      // [256][64][32]
    float* __restrict__ ph_ws,      // [256][64]
    float* __restrict__ out_ph)     // [256][64]
{
  const int n  = blockIdx.x;
  const int bt = blockIdx.y * 64;
  const int t  = threadIdx.x;
  const int w  = t >> 6, l = t & 63;
  const int lr = l & 15, lg = l >> 4;

  __shared__ unsigned short hb[64][72];    // [row][k] bf16, 144B rows
  __shared__ unsigned short wbT[64][72];   // [col][k] bf16, 144B rows

  f32x4 acc[4] = {};   // nf=0,1 -> xm cols ; nf=2,3 -> dl cols

  const int hr = t >> 2,       hc  = (t & 3) * 16;   // h staging
  const int wk = (t >> 3) * 2, wcq = (t & 7) * 4;    // W staging
  const float* hsrc  = h  + (bt + hr) * Ll + hc;
  const float* wcsrc = Wc + n * (Ll * Dd) + wk * Dd + wcq;
  const float* wosrc = Wo + n * (Ll * Dd) + wk * Dd + wcq;

  float4 hp0, hp1, hp2, hp3, c0, c1, o0, o1;
  auto fetch = [&](int k0) {
    const float* hs = hsrc + k0;
    hp0 = *(const float4*)(hs);
    hp1 = *(const float4*)(hs + 4);
    hp2 = *(const float4*)(hs + 8);
    hp3 = *(const float4*)(hs + 12);
    const float* ws = wcsrc + k0 * Dd;
    c0 = *(const float4*)(ws);
    c1 = *(const float4*)(ws + Dd);
    const float* os = wosrc + k0 * Dd;
    o0 = *(const float4*)(os);
    o1 = *(const float4*)(os + Dd);
  };

  fetch(0);
  for (int ch = 0; ch < 8; ch++) {
    __syncthreads();
    {
      unsigned short* hd = &hb[hr][hc];
      hd[0]  = f2bf(hp0.x); hd[1]  = f2bf(hp0.y);
      hd[2]  = f2bf(hp0.z); hd[3]  = f2bf(hp0.w);
      hd[4]  = f2bf(hp1.x); hd[5]  = f2bf(hp1.y);
      hd[6]  = f2bf(hp1.z); hd[7]  = f2bf(hp1.w);
      hd[8]  = f2bf(hp2.x); hd[9]  = f2bf(hp2.y);
      hd[10] = f2bf(hp2.z); hd[11] = f2bf(hp2.w);
      hd[12] = f2bf(hp3.x); hd[13] = f2bf(hp3.y);
      hd[14] = f2bf(hp3.z); hd[15] = f2bf(hp3.w);
    }
    {
      const float* c0p = &c0.x; const float* c1p = &c1.x;
      const float* o0p = &o0.x; const float* o1p = &o1.x;
      #pragma unroll
      for (int i = 0; i < 4; i++) {
        unsigned int pc = (unsigned int)f2bf(c0p[i]) |
                          ((unsigned int)f2bf(c1p[i]) << 16);
        *(unsigned int*)&wbT[wcq + i][wk] = pc;
        unsigned int po = (unsigned int)f2bf(o0p[i]) |
                          ((unsigned int)f2bf(o1p[i]) << 16);
        *(unsigned int*)&wbT[32 + wcq + i][wk] = po;
      }
    }
    __syncthreads();
    if (ch < 7) fetch((ch + 1) * 64);
    const int arow = w * 16 + lr;
    #pragma unroll
    for (int ks = 0; ks < 2; ks++) {
      const int ko = ks * 32 + lg * 8;
      const short8 av = *(const short8*)&hb[arow][ko];
      #pragma unroll
      for (int nf = 0; nf < 4; nf++) {
        const short8 bv = *(const short8*)&wbT[nf * 16 + lr][ko];
        acc[nf] = __builtin_amdgcn_mfma_f32_16x16x32_bf16(av, bv, acc[nf],
                                                          0, 0, 0);
      }
    }
  }

  const float bc0 = bc[n * Dd + lr],      bc1 = bc[n * Dd + 16 + lr];
  const float bo0 = bo[n * Dd + lr],      bo1 = bo[n * Dd + 16 + lr];
  const float wp0 = Wp[n * 64 + lr],      wp1 = Wp[n * 64 + 16 + lr];
  const float wp2 = Wp[n * 64 + 32 + lr], wp3 = Wp[n * 64 + 48 + lr];
  const float bpv = bp[n];

  #pragma unroll
  for (int q = 0; q < 4; q++) {
    const int b = bt + w * 16 + lg * 4 + q;
    const float xm0  = acc[0][q] + bc0;
    const float xm1  = acc[1][q] + bc1;
    const float pre0 = acc[2][q] + bo0;
    const float pre1 = acc[3][q] + bo1;
    // stable softplus = max(x,0) + log1p(exp(-|x|))
    const float dl0 = fmaxf(pre0, 0.f) + log1pf(expf(-fabsf(pre0)));
    const float dl1 = fmaxf(pre1, 0.f) + log1pf(expf(-fabsf(pre1)));
    float* xp = xm_ws + b * 2048 + n * Dd;
    float* dp = dl_ws + b * 2048 + n * Dd;
    xp[lr] = xm0;  xp[16 + lr] = xm1;
    dp[lr] = dl0;  dp[16 + lr] = dl1;
    float pp = xm0 * wp0 + xm1 * wp1 + dl0 * wp2 + dl1 * wp3;
    pp += __shfl_xor(pp, 1);
    pp += __shfl_xor(pp, 2);
    pp += __shfl_xor(pp, 4);
    pp += __shfl_xor(pp, 8);
    if (lr == 0) {
      const float ph = 1.f / (1.f + expf(-(pp + bpv)));
      ph_ws[b * 64 + n] = ph;
      out_ph[b * 64 + n] = ph;
    }
  }
}

// ---------------------------------------------------------------------------
// Kernel B v3: pairwise intersection volumes.  One block (512 thr) per b.
// ---------------------------------------------------------------------------
__global__ __launch_bounds__(512) void kB(
    const float* __restrict__ xm_ws,
    const float* __restrict__ dl_ws,
    float* __restrict__ out_V)      // [256][64][64]
{
  const int b = blockIdx.x, t = threadIdx.x;
  __shared__ float lo[64][36];
  __shared__ float hi[64][36];
  __shared__ float rvol[64];

  {
    const int n = t >> 3, dd = (t & 7) * 4;
    float4 x = *(const float4*)(xm_ws + b * 2048 + n * Dd + dd);
    float4 g = *(const float4*)(dl_ws + b * 2048 + n * Dd + dd);
    lo[n][dd + 0] = x.x - g.x;  hi[n][dd + 0] = x.x + g.x;
    lo[n][dd + 1] = x.y - g.y;  hi[n][dd + 1] = x.y + g.y;
    lo[n][dd + 2] = x.z - g.z;  hi[n][dd + 2] = x.z + g.z;
    lo[n][dd + 3] = x.w - g.w;  hi[n][dd + 3] = x.w + g.w;
  }
  if (t < 64) {
    const float* dp = dl_ws + b * 2048 + t * Dd;
    float p = 1.f;
    #pragma unroll
    for (int dd = 0; dd < 32; dd++) p *= dp[dd] + EPS;
    rvol[t] = 1.f / p;
  }
  __syncthreads();

  const int i0 = t >> 6;    // wave id -> i uniform per wave
  const int j  = t & 63;
  #pragma unroll 1
  for (int it = 0; it < 8; it++) {
    const int i = i0 + 8 * it;
    float prod = 1.f;
    #pragma unroll
    for (int dd = 0; dd < 32; dd += 4) {
      float4 hj = *(const float4*)&hi[j][dd];
      float4 lj = *(const float4*)&lo[j][dd];
      float4 hv = *(const float4*)&hi[i][dd];   // broadcast
      float4 lv = *(const float4*)&lo[i][dd];   // broadcast
      float v0 = fmaxf(fminf(hv.x, hj.x) - fmaxf(lv.x, lj.x), 0.f) * 0.5f + EPS;
      float v1 = fmaxf(fminf(hv.y, hj.y) - fmaxf(lv.y, lj.y), 0.f) * 0.5f + EPS;
      float v2 = fmaxf(fminf(hv.z, hj.z) - fmaxf(lv.z, lj.z), 0.f) * 0.5f + EPS;
      float v3 = fmaxf(fminf(hv.w, hj.w) - fmaxf(lv.w, lj.w), 0.f) * 0.5f + EPS;
      prod *= v0 * v1 * v2 * v3;
    }
    out_V[b * 4096 + i * 64 + j] = prod * rvol[j];
  }
}

// ---------------------------------------------------------------------------
// Kernel C1 v4: split-K GEMM partials, grid (8,32) x 512 thr (8 waves/CU).
//   A = concat([aligned, V]) : [256][8192], W = [W1; W2] : [8192][100]
//   Block: 32 rows x 100 cols, K-slice 256 (4 chunks of 64).
//   Thread tile: 1 row x 8 cols.  VALU-bound (32 VALU vs ~12 LDS cyc /kk/CU).
// ---------------------------------------------------------------------------
__global__ __launch_bounds__(512) void kC1(
    const float* __restrict__ xm_ws,   // [256][2048]
    const float* __restrict__ dl_ws,   // [256][2048]
    const float* __restrict__ ph_ws,   // [256][64]
    const float* __restrict__ Vb,      // [256][4096] (from d_out)
    const float* __restrict__ W1,      // [4096][100]
    const float* __restrict__ W2,      // [4096][100]
    float* __restrict__ part)          // [32][256][100]
{
  const int bg = blockIdx.x;           // 8 row-groups of 32
  const int s  = blockIdx.y;           // 32 K-slices
  const bool isV = (s >= 16);
  const int m0 = (s & 15) * 256;       // type-local K offset
  const float* __restrict__ W = isV ? W2 : W1;

  __shared__ float Wt[64][132];        // [kk][col]
  __shared__ float At[64][33];         // [kk][row]

  const int t  = threadIdx.x;          // 0..511
  const int tx = t & 15;               // col quads tx, tx+16
  const int ty = t >> 4;               // row (0..31)

  float acc[8] = {};

  // staging maps (512 threads)
  const int wrw = t >> 3, wq = t & 7;          // W: row, quad lane
  const int ar = t & 31, ak4 = (t >> 5) * 4;   // A: row, 4-kk base
  const int brow_s = bg * 32 + ar;

  float4 wreg[4];
  float4 areg;
  auto load_chunk = [&](int mbase) {
    const float* wr = W + (mbase + wrw) * Cc;
    #pragma unroll
    for (int j = 0; j < 4; j++) {
      const int c = (wq + j * 8) * 4;
      wreg[j] = (c < Cc) ? *(const float4*)(wr + c)
                         : make_float4(0.f, 0.f, 0.f, 0.f);
    }
    const int mk = mbase + ak4;
    if (!isV) {
      const int nn = mk >> 6, sub = mk & 63;
      const float phv = ph_ws[brow_s * 64 + nn];
      const float* src = (sub < 32)
          ? (xm_ws + brow_s * 2048 + nn * Dd + sub)
          : (dl_ws + brow_s * 2048 + nn * Dd + (sub - 32));
      areg = *(const float4*)(src);
      areg.x *= phv; areg.y *= phv; areg.z *= phv; areg.w *= phv;
    } else {
      areg = *(const float4*)(Vb + brow_s * 4096 + mk);
    }
  };

  load_chunk(m0);
  for (int ch = 0; ch < 4; ch++) {
    __syncthreads();
    #pragma unroll
    for (int j = 0; j < 4; j++) {
      const int c = (wq + j * 8) * 4;
      if (c < Cc) *(float4*)&Wt[wrw][c] = wreg[j];
    }
    At[ak4 + 0][ar] = areg.x;
    At[ak4 + 1][ar] = areg.y;
    At[ak4 + 2][ar] = areg.z;
    At[ak4 + 3][ar] = areg.w;
    __syncthreads();
    if (ch < 3) load_chunk(m0 + (ch + 1) * 64);
    #pragma unroll 8
    for (int kk = 0; kk < 64; kk++) {
      const float av = At[kk][ty];
      const float4 wlo = *(const float4*)&Wt[kk][tx * 4];
      const float4 whi = *(const float4*)&Wt[kk][(tx + 16) * 4];
      acc[0] += av * wlo.x; acc[1] += av * wlo.y;
      acc[2] += av * wlo.z; acc[3] += av * wlo.w;
      acc[4] += av * whi.x; acc[5] += av * whi.y;
      acc[6] += av * whi.z; acc[7] += av * whi.w;
    }
  }

  {
    float* pr = part + (s * 256 + bg * 32 + ty) * Cc;
    #pragma unroll
    for (int q = 0; q < 2; q++) {
      const int c0 = (tx + q * 16) * 4;
      if (c0 < Cc) {
        pr[c0 + 0] = acc[q * 4 + 0];
        pr[c0 + 1] = acc[q * 4 + 1];
        pr[c0 + 2] = acc[q * 4 + 2];
        pr[c0 + 3] = acc[q * 4 + 3];
      }
    }
  }
}

// ---------------------------------------------------------------------------
// Kernel C2: reduce 32 partials + biases -> y.  grid 100 x 256 threads.
// ---------------------------------------------------------------------------
__global__ __launch_bounds__(256) void kC2(
    const float* __restrict__ part,    // [32][25600]
    const float* __restrict__ b1,
    const float* __restrict__ b2,
    float* __restrict__ out_y)         // [256][100] flat = 25600
{
  const int o = blockIdx.x * 256 + threadIdx.x;   // 0..25599
  const int c = o % Cc;
  float sum = b1[c] + b2[c];
  #pragma unroll
  for (int s = 0; s < 32; s++) sum += part[s * 25600 + o];
  out_y[o] = sum;
}

// ---------------------------------------------------------------------------
extern "C" void kernel_launch(void* const* d_in, const int* in_sizes, int n_in,
                              void* d_out, int out_size, void* d_ws, size_t ws_size,
                              hipStream_t stream) {
  const float* h  = (const float*)d_in[0];
  const float* Wc = (const float*)d_in[1];
  const float* bc = (const float*)d_in[2];
  const float* Wo = (const float*)d_in[3];
  const float* bo = (const float*)d_in[4];
  const float* Wp = (const float*)d_in[5];
  const float* bp = (const float*)d_in[6];
  const float* W1 = (const float*)d_in[7];
  const float* b1 = (const float*)d_in[8];
  const float* W2 = (const float*)d_in[9];
  const float* b2 = (const float*)d_in[10];

  float* out    = (float*)d_out;
  float* out_y  = out;                         // [256][100]
  float* out_ph = out + Bb * Cc;               // [256][64]
  float* out_V  = out + Bb * Cc + Bb * Nn;     // [256][64][64]

  float* xm   = (float*)d_ws;              // 524288 f32 (2 MB)
  float* dl   = xm + Bb * Nn * Dd;         // 524288 f32 (2 MB)
  float* ph   = dl + Bb * Nn * Dd;         // 16384 f32
  float* part = ph + Bb * Nn;              // 32*25600 f32 (3.28 MB)

  kA<<<dim3(Nn, Bb / 64), 256, 0, stream>>>(h, Wc, bc, Wo, bo, Wp, bp,
                                            xm, dl, ph, out_ph);
  kB<<<Bb, 512, 0, stream>>>(xm, dl, out_V);
  kC1<<<dim3(8, 32), 512, 0, stream>>>(xm, dl, ph, (const float*)out_V,
                                       W1, W2, part);
  kC2<<<100, 256, 0, stream>>>(part, b1, b2, out_y);
}

// Round 10
// 48.960 us; speedup vs baseline: 2.9845x; 1.0509x over previous
//
#include <hip/hip_runtime.h>
#include <hip/hip_bf16.h>
#include <cstdint>

// Problem constants (ConceptBoxModel): B=256, L=512, N=64, D=32, C=100
constexpr int Bb = 256, Ll = 512, Nn = 64, Dd = 32, Cc = 100;
constexpr float EPS = 1e-6f;

typedef __attribute__((ext_vector_type(8))) short short8;   // 8 bf16
typedef __attribute__((ext_vector_type(4))) float f32x4;    // MFMA C/D frag

__device__ __forceinline__ unsigned short f2bf(float f) {
  union { float f; uint32_t u; } v; v.f = f;
  uint32_t r = v.u + 0x7FFFu + ((v.u >> 16) & 1u);   // RNE
  return (unsigned short)(r >> 16);
}

// ---------------------------------------------------------------------------
// Kernel A v6 (MFMA): x_m = h@Wc + bc ; delta = softplus(h@Wo + bo) ; p_hat
// Also initializes out_y = b1 + b2 (kC atomicAdds partial GEMM sums onto it).
// ---------------------------------------------------------------------------
__global__ __launch_bounds__(256) void kA(
    const float* __restrict__ h,    // [256][512]
    const float* __restrict__ Wc,   // [64][512][32]
    const float* __restrict__ bc,   // [64][32]
    const float* __restrict__ Wo,
    const float* __restrict__ bo,
    const float* __restrict__ Wp,   // [64][64]
    const float* __restrict__ bp,   // [64]
    const float* __restrict__ b1,   // [100]
    const float* __restrict__ b2,   // [100]
    float* __restrict__ xm_ws,      // [256][64][32]
    float* __restrict__ dl_ws,      // [256][64][32]
    float* __restrict__ ph_ws,      // [256][64]
    float* __restrict__ out_ph,     // [256][64]
    float* __restrict__ out_y)      // [256][100] (init only)
{
  const int n  = blockIdx.x;
  const int bt = blockIdx.y * 64;
  const int t  = threadIdx.x;
  const int w  = t >> 6, l = t & 63;
  const int lr = l & 15, lg = l >> 4;

  // init y with biases (one block per output row)
  {
    const int bid = blockIdx.x + Nn * blockIdx.y;   // 0..255
    if (t < Cc) out_y[bid * Cc + t] = b1[t] + b2[t];
  }

  __shared__ unsigned short hb[64][72];    // [row][k] bf16, 144B rows
  __shared__ unsigned short wbT[64][72];   // [col][k] bf16, 144B rows

  f32x4 acc[4] = {};   // nf=0,1 -> xm cols ; nf=2,3 -> dl cols

  const int hr = t >> 2,       hc  = (t & 3) * 16;   // h staging
  const int wk = (t >> 3) * 2, wcq = (t & 7) * 4;    // W staging
  const float* hsrc  = h  + (bt + hr) * Ll + hc;
  const float* wcsrc = Wc + n * (Ll * Dd) + wk * Dd + wcq;
  const float* wosrc = Wo + n * (Ll * Dd) + wk * Dd + wcq;

  float4 hp0, hp1, hp2, hp3, c0, c1, o0, o1;
  auto fetch = [&](int k0) {
    const float* hs = hsrc + k0;
    hp0 = *(const float4*)(hs);
    hp1 = *(const float4*)(hs + 4);
    hp2 = *(const float4*)(hs + 8);
    hp3 = *(const float4*)(hs + 12);
    const float* ws = wcsrc + k0 * Dd;
    c0 = *(const float4*)(ws);
    c1 = *(const float4*)(ws + Dd);
    const float* os = wosrc + k0 * Dd;
    o0 = *(const float4*)(os);
    o1 = *(const float4*)(os + Dd);
  };

  fetch(0);
  for (int ch = 0; ch < 8; ch++) {
    __syncthreads();
    {
      unsigned short* hd = &hb[hr][hc];
      hd[0]  = f2bf(hp0.x); hd[1]  = f2bf(hp0.y);
      hd[2]  = f2bf(hp0.z); hd[3]  = f2bf(hp0.w);
      hd[4]  = f2bf(hp1.x); hd[5]  = f2bf(hp1.y);
      hd[6]  = f2bf(hp1.z); hd[7]  = f2bf(hp1.w);
      hd[8]  = f2bf(hp2.x); hd[9]  = f2bf(hp2.y);
      hd[10] = f2bf(hp2.z); hd[11] = f2bf(hp2.w);
      hd[12] = f2bf(hp3.x); hd[13] = f2bf(hp3.y);
      hd[14] = f2bf(hp3.z); hd[15] = f2bf(hp3.w);
    }
    {
      const float* c0p = &c0.x; const float* c1p = &c1.x;
      const float* o0p = &o0.x; const float* o1p = &o1.x;
      #pragma unroll
      for (int i = 0; i < 4; i++) {
        unsigned int pc = (unsigned int)f2bf(c0p[i]) |
                          ((unsigned int)f2bf(c1p[i]) << 16);
        *(unsigned int*)&wbT[wcq + i][wk] = pc;
        unsigned int po = (unsigned int)f2bf(o0p[i]) |
                          ((unsigned int)f2bf(o1p[i]) << 16);
        *(unsigned int*)&wbT[32 + wcq + i][wk] = po;
      }
    }
    __syncthreads();
    if (ch < 7) fetch((ch + 1) * 64);
    const int arow = w * 16 + lr;
    #pragma unroll
    for (int ks = 0; ks < 2; ks++) {
      const int ko = ks * 32 + lg * 8;
      const short8 av = *(const short8*)&hb[arow][ko];
      #pragma unroll
      for (int nf = 0; nf < 4; nf++) {
        const short8 bv = *(const short8*)&wbT[nf * 16 + lr][ko];
        acc[nf] = __builtin_amdgcn_mfma_f32_16x16x32_bf16(av, bv, acc[nf],
                                                          0, 0, 0);
      }
    }
  }

  const float bc0 = bc[n * Dd + lr],      bc1 = bc[n * Dd + 16 + lr];
  const float bo0 = bo[n * Dd + lr],      bo1 = bo[n * Dd + 16 + lr];
  const float wp0 = Wp[n * 64 + lr],      wp1 = Wp[n * 64 + 16 + lr];
  const float wp2 = Wp[n * 64 + 32 + lr], wp3 = Wp[n * 64 + 48 + lr];
  const float bpv = bp[n];

  #pragma unroll
  for (int q = 0; q < 4; q++) {
    const int b = bt + w * 16 + lg * 4 + q;
    const float xm0  = acc[0][q] + bc0;
    const float xm1  = acc[1][q] + bc1;
    const float pre0 = acc[2][q] + bo0;
    const float pre1 = acc[3][q] + bo1;
    // stable softplus = max(x,0) + log1p(exp(-|x|))
    const float dl0 = fmaxf(pre0, 0.f) + log1pf(expf(-fabsf(pre0)));
    const float dl1 = fmaxf(pre1, 0.f) + log1pf(expf(-fabsf(pre1)));
    float* xp = xm_ws + b * 2048 + n * Dd;
    float* dp = dl_ws + b * 2048 + n * Dd;
    xp[lr] = xm0;  xp[16 + lr] = xm1;
    dp[lr] = dl0;  dp[16 + lr] = dl1;
    float pp = xm0 * wp0 + xm1 * wp1 + dl0 * wp2 + dl1 * wp3;
    pp += __shfl_xor(pp, 1);
    pp += __shfl_xor(pp, 2);
    pp += __shfl_xor(pp, 4);
    pp += __shfl_xor(pp, 8);
    if (lr == 0) {
      const float ph = 1.f / (1.f + expf(-(pp + bpv)));
      ph_ws[b * 64 + n] = ph;
      out_ph[b * 64 + n] = ph;
    }
  }
}

// ---------------------------------------------------------------------------
// Kernel B v3: pairwise intersection volumes.  One block (512 thr) per b.
// ---------------------------------------------------------------------------
__global__ __launch_bounds__(512) void kB(
    const float* __restrict__ xm_ws,
    const float* __restrict__ dl_ws,
    float* __restrict__ out_V)      // [256][64][64]
{
  const int b = blockIdx.x, t = threadIdx.x;
  __shared__ float lo[64][36];
  __shared__ float hi[64][36];
  __shared__ float rvol[64];

  {
    const int n = t >> 3, dd = (t & 7) * 4;
    float4 x = *(const float4*)(xm_ws + b * 2048 + n * Dd + dd);
    float4 g = *(const float4*)(dl_ws + b * 2048 + n * Dd + dd);
    lo[n][dd + 0] = x.x - g.x;  hi[n][dd + 0] = x.x + g.x;
    lo[n][dd + 1] = x.y - g.y;  hi[n][dd + 1] = x.y + g.y;
    lo[n][dd + 2] = x.z - g.z;  hi[n][dd + 2] = x.z + g.z;
    lo[n][dd + 3] = x.w - g.w;  hi[n][dd + 3] = x.w + g.w;
  }
  if (t < 64) {
    const float* dp = dl_ws + b * 2048 + t * Dd;
    float p = 1.f;
    #pragma unroll
    for (int dd = 0; dd < 32; dd++) p *= dp[dd] + EPS;
    rvol[t] = 1.f / p;
  }
  __syncthreads();

  const int i0 = t >> 6;    // wave id -> i uniform per wave
  const int j  = t & 63;
  #pragma unroll 1
  for (int it = 0; it < 8; it++) {
    const int i = i0 + 8 * it;
    float prod = 1.f;
    #pragma unroll
    for (int dd = 0; dd < 32; dd += 4) {
      float4 hj = *(const float4*)&hi[j][dd];
      float4 lj = *(const float4*)&lo[j][dd];
      float4 hv = *(const float4*)&hi[i][dd];   // broadcast
      float4 lv = *(const float4*)&lo[i][dd];   // broadcast
      float v0 = fmaxf(fminf(hv.x, hj.x) - fmaxf(lv.x, lj.x), 0.f) * 0.5f + EPS;
      float v1 = fmaxf(fminf(hv.y, hj.y) - fmaxf(lv.y, lj.y), 0.f) * 0.5f + EPS;
      float v2 = fmaxf(fminf(hv.z, hj.z) - fmaxf(lv.z, lj.z), 0.f) * 0.5f + EPS;
      float v3 = fmaxf(fminf(hv.w, hj.w) - fmaxf(lv.w, lj.w), 0.f) * 0.5f + EPS;
      prod *= v0 * v1 * v2 * v3;
    }
    out_V[b * 4096 + i * 64 + j] = prod * rvol[j];
  }
}

// ---------------------------------------------------------------------------
// Kernel C v5 (MFMA split-K): y += [aligned|V] @ [W1;W2]  (bf16 MFMA)
// grid (Mg=4, s=64) = 256 blocks x 256 thr (4 waves).
// Block: 64 rows x 100(112p) cols x K-slice 128 (4 chunks of 32).
// s<32: aligned half (k=s*128 of 4096); s>=32: V half.
// Wave w: rows w*16..+15, 7 col-frags.  Epilogue: atomicAdd into out_y
// (pre-initialized with b1+b2 by kA; stream order guarantees init first).
// ---------------------------------------------------------------------------
__global__ __launch_bounds__(256) void kC(
    const float* __restrict__ xm_ws,   // [256][2048]
    const float* __restrict__ dl_ws,   // [256][2048]
    const float* __restrict__ ph_ws,   // [256][64]
    const float* __restrict__ Vb,      // [256][4096] (from d_out)
    const float* __restrict__ W1,      // [4096][100]
    const float* __restrict__ W2,      // [4096][100]
    float* __restrict__ out_y)         // [256][100] accumulate
{
  const int Mg = blockIdx.x;           // 4 row-groups of 64
  const int s  = blockIdx.y;           // 64 K-slices of 128
  const bool isV = (s >= 32);
  const int m0 = (s & 31) * 128;       // offset within half
  const float* __restrict__ W = isV ? W2 : W1;
  const int b0 = Mg * 64;

  __shared__ unsigned short Ab[64][40];    // [row][k] bf16, 80B rows
  __shared__ unsigned short Wb[112][40];   // [col][k] bf16

  const int t = threadIdx.x;
  const int w = t >> 6, l = t & 63;
  const int lr = l & 15, lg = l >> 4;

  f32x4 acc[7] = {};

  // A staging: ar = row (64), ak8 = 8-k run base
  const int ar = t >> 2, ak8 = (t & 3) * 8;
  const int arow = b0 + ar;
  // W staging: wc = col (128 lanes), wkb + 2i = k-rows
  const int wc = t & 127, wkb = t >> 7;

  float4 a0, a1;
  float wv[16];

  auto fetch = [&](int ch) {
    const int kb = m0 + ch * 32;
    const int mk = kb + ak8;
    if (!isV) {
      const int nn = mk >> 6, sub = mk & 63;
      const float phv = ph_ws[arow * 64 + nn];
      const float* src = (sub < 32)
          ? (xm_ws + arow * 2048 + nn * Dd + sub)
          : (dl_ws + arow * 2048 + nn * Dd + (sub - 32));
      a0 = *(const float4*)(src);
      a1 = *(const float4*)(src + 4);
      a0.x *= phv; a0.y *= phv; a0.z *= phv; a0.w *= phv;
      a1.x *= phv; a1.y *= phv; a1.z *= phv; a1.w *= phv;
    } else {
      const float* src = Vb + arow * 4096 + mk;
      a0 = *(const float4*)(src);
      a1 = *(const float4*)(src + 4);
    }
    if (wc < Cc) {
      #pragma unroll
      for (int i = 0; i < 16; i++)
        wv[i] = W[(kb + wkb + 2 * i) * Cc + wc];
    }
  };

  fetch(0);
  for (int ch = 0; ch < 4; ch++) {
    __syncthreads();   // previous chunk's readers done
    // ---- A -> LDS (16B contiguous per thread) ----
    {
      unsigned short* ad = &Ab[ar][ak8];
      ad[0] = f2bf(a0.x); ad[1] = f2bf(a0.y);
      ad[2] = f2bf(a0.z); ad[3] = f2bf(a0.w);
      ad[4] = f2bf(a1.x); ad[5] = f2bf(a1.y);
      ad[6] = f2bf(a1.z); ad[7] = f2bf(a1.w);
    }
    // ---- W -> LDS transposed [col][k] ----
    if (wc < Cc) {
      #pragma unroll
      for (int i = 0; i < 16; i++)
        Wb[wc][wkb + 2 * i] = f2bf(wv[i]);
    } else if (wc < 112) {
      #pragma unroll
      for (int i = 0; i < 16; i++)
        Wb[wc][wkb + 2 * i] = 0;
    }
    __syncthreads();
    if (ch < 3) fetch(ch + 1);
    // ---- MFMA: one 16x16x32 k-step per chunk ----
    const short8 av = *(const short8*)&Ab[w * 16 + lr][lg * 8];
    #pragma unroll
    for (int nf = 0; nf < 7; nf++) {
      const short8 bv = *(const short8*)&Wb[nf * 16 + lr][lg * 8];
      acc[nf] = __builtin_amdgcn_mfma_f32_16x16x32_bf16(av, bv, acc[nf],
                                                        0, 0, 0);
    }
  }

  // ---- epilogue: atomic accumulate (col=lane&15, row=(lane>>4)*4+q) ----
  #pragma unroll
  for (int nf = 0; nf < 7; nf++) {
    const int col = nf * 16 + lr;
    if (col < Cc) {
      #pragma unroll
      for (int q = 0; q < 4; q++) {
        const int row = b0 + w * 16 + lg * 4 + q;
        atomicAdd(out_y + row * Cc + col, acc[nf][q]);
      }
    }
  }
}

// ---------------------------------------------------------------------------
extern "C" void kernel_launch(void* const* d_in, const int* in_sizes, int n_in,
                              void* d_out, int out_size, void* d_ws, size_t ws_size,
                              hipStream_t stream) {
  const float* h  = (const float*)d_in[0];
  const float* Wc = (const float*)d_in[1];
  const float* bc = (const float*)d_in[2];
  const float* Wo = (const float*)d_in[3];
  const float* bo = (const float*)d_in[4];
  const float* Wp = (const float*)d_in[5];
  const float* bp = (const float*)d_in[6];
  const float* W1 = (const float*)d_in[7];
  const float* b1 = (const float*)d_in[8];
  const float* W2 = (const float*)d_in[9];
  const float* b2 = (const float*)d_in[10];

  float* out    = (float*)d_out;
  float* out_y  = out;                         // [256][100]
  float* out_ph = out + Bb * Cc;               // [256][64]
  float* out_V  = out + Bb * Cc + Bb * Nn;     // [256][64][64]

  float* xm = (float*)d_ws;              // 524288 f32 (2 MB)
  float* dl = xm + Bb * Nn * Dd;         // 524288 f32 (2 MB)
  float* ph = dl + Bb * Nn * Dd;         // 16384 f32

  kA<<<dim3(Nn, Bb / 64), 256, 0, stream>>>(h, Wc, bc, Wo, bo, Wp, bp,
                                            b1, b2, xm, dl, ph, out_ph, out_y);
  kB<<<Bb, 512, 0, stream>>>(xm, dl, out_V);
  kC<<<dim3(4, 64), 256, 0, stream>>>(xm, dl, ph, (const float*)out_V,
                                      W1, W2, out_y);
}

// Round 11
// 48.639 us; speedup vs baseline: 3.0041x; 1.0066x over previous
//
#include <hip/hip_runtime.h>
#include <hip/hip_bf16.h>
#include <cstdint>

// Problem constants (ConceptBoxModel): B=256, L=512, N=64, D=32, C=100
constexpr int Bb = 256, Ll = 512, Nn = 64, Dd = 32, Cc = 100;
constexpr float EPS = 1e-6f;

typedef __attribute__((ext_vector_type(8))) short short8;   // 8 bf16
typedef __attribute__((ext_vector_type(4))) float f32x4;    // MFMA C/D frag

__device__ __forceinline__ unsigned short f2bf(float f) {
  union { float f; uint32_t u; } v; v.f = f;
  uint32_t r = v.u + 0x7FFFu + ((v.u >> 16) & 1u);   // RNE
  return (unsigned short)(r >> 16);
}

// ---------------------------------------------------------------------------
// Kernel A v7 (MFMA): x_m = h@Wc + bc ; delta = softplus(h@Wo + bo) ; p_hat
// Writes: xm/dl f32 (for kB), aligned = box*p_hat as bf16 into abuf[b][0:4096]
// (MFMA-ready for kC), out_ph, and inits out_y = b1 + b2.
// ---------------------------------------------------------------------------
__global__ __launch_bounds__(256) void kA(
    const float* __restrict__ h,    // [256][512]
    const float* __restrict__ Wc,   // [64][512][32]
    const float* __restrict__ bc,   // [64][32]
    const float* __restrict__ Wo,
    const float* __restrict__ bo,
    const float* __restrict__ Wp,   // [64][64]
    const float* __restrict__ bp,   // [64]
    const float* __restrict__ b1,   // [100]
    const float* __restrict__ b2,   // [100]
    float* __restrict__ xm_ws,      // [256][64][32]
    float* __restrict__ dl_ws,      // [256][64][32]
    unsigned short* __restrict__ abuf,  // [256][8192] bf16 (first half)
    float* __restrict__ out_ph,     // [256][64]
    float* __restrict__ out_y)      // [256][100] (init only)
{
  const int n  = blockIdx.x;
  const int bt = blockIdx.y * 64;
  const int t  = threadIdx.x;
  const int w  = t >> 6, l = t & 63;
  const int lr = l & 15, lg = l >> 4;

  // init y with biases (one block per output row)
  {
    const int bid = blockIdx.x + Nn * blockIdx.y;   // 0..255
    if (t < Cc) out_y[bid * Cc + t] = b1[t] + b2[t];
  }

  __shared__ unsigned short hb[64][72];    // [row][k] bf16, 144B rows
  __shared__ unsigned short wbT[64][72];   // [col][k] bf16, 144B rows

  f32x4 acc[4] = {};   // nf=0,1 -> xm cols ; nf=2,3 -> dl cols

  const int hr = t >> 2,       hc  = (t & 3) * 16;   // h staging
  const int wk = (t >> 3) * 2, wcq = (t & 7) * 4;    // W staging
  const float* hsrc  = h  + (bt + hr) * Ll + hc;
  const float* wcsrc = Wc + n * (Ll * Dd) + wk * Dd + wcq;
  const float* wosrc = Wo + n * (Ll * Dd) + wk * Dd + wcq;

  float4 hp0, hp1, hp2, hp3, c0, c1, o0, o1;
  auto fetch = [&](int k0) {
    const float* hs = hsrc + k0;
    hp0 = *(const float4*)(hs);
    hp1 = *(const float4*)(hs + 4);
    hp2 = *(const float4*)(hs + 8);
    hp3 = *(const float4*)(hs + 12);
    const float* ws = wcsrc + k0 * Dd;
    c0 = *(const float4*)(ws);
    c1 = *(const float4*)(ws + Dd);
    const float* os = wosrc + k0 * Dd;
    o0 = *(const float4*)(os);
    o1 = *(const float4*)(os + Dd);
  };

  fetch(0);
  for (int ch = 0; ch < 8; ch++) {
    __syncthreads();
    {
      unsigned short* hd = &hb[hr][hc];
      hd[0]  = f2bf(hp0.x); hd[1]  = f2bf(hp0.y);
      hd[2]  = f2bf(hp0.z); hd[3]  = f2bf(hp0.w);
      hd[4]  = f2bf(hp1.x); hd[5]  = f2bf(hp1.y);
      hd[6]  = f2bf(hp1.z); hd[7]  = f2bf(hp1.w);
      hd[8]  = f2bf(hp2.x); hd[9]  = f2bf(hp2.y);
      hd[10] = f2bf(hp2.z); hd[11] = f2bf(hp2.w);
      hd[12] = f2bf(hp3.x); hd[13] = f2bf(hp3.y);
      hd[14] = f2bf(hp3.z); hd[15] = f2bf(hp3.w);
    }
    {
      const float* c0p = &c0.x; const float* c1p = &c1.x;
      const float* o0p = &o0.x; const float* o1p = &o1.x;
      #pragma unroll
      for (int i = 0; i < 4; i++) {
        unsigned int pc = (unsigned int)f2bf(c0p[i]) |
                          ((unsigned int)f2bf(c1p[i]) << 16);
        *(unsigned int*)&wbT[wcq + i][wk] = pc;
        unsigned int po = (unsigned int)f2bf(o0p[i]) |
                          ((unsigned int)f2bf(o1p[i]) << 16);
        *(unsigned int*)&wbT[32 + wcq + i][wk] = po;
      }
    }
    __syncthreads();
    if (ch < 7) fetch((ch + 1) * 64);
    const int arow = w * 16 + lr;
    #pragma unroll
    for (int ks = 0; ks < 2; ks++) {
      const int ko = ks * 32 + lg * 8;
      const short8 av = *(const short8*)&hb[arow][ko];
      #pragma unroll
      for (int nf = 0; nf < 4; nf++) {
        const short8 bv = *(const short8*)&wbT[nf * 16 + lr][ko];
        acc[nf] = __builtin_amdgcn_mfma_f32_16x16x32_bf16(av, bv, acc[nf],
                                                          0, 0, 0);
      }
    }
  }

  const float bc0 = bc[n * Dd + lr],      bc1 = bc[n * Dd + 16 + lr];
  const float bo0 = bo[n * Dd + lr],      bo1 = bo[n * Dd + 16 + lr];
  const float wp0 = Wp[n * 64 + lr],      wp1 = Wp[n * 64 + 16 + lr];
  const float wp2 = Wp[n * 64 + 32 + lr], wp3 = Wp[n * 64 + 48 + lr];
  const float bpv = bp[n];

  #pragma unroll
  for (int q = 0; q < 4; q++) {
    const int b = bt + w * 16 + lg * 4 + q;
    const float xm0  = acc[0][q] + bc0;
    const float xm1  = acc[1][q] + bc1;
    const float pre0 = acc[2][q] + bo0;
    const float pre1 = acc[3][q] + bo1;
    // stable softplus = max(x,0) + log1p(exp(-|x|))
    const float dl0 = fmaxf(pre0, 0.f) + log1pf(expf(-fabsf(pre0)));
    const float dl1 = fmaxf(pre1, 0.f) + log1pf(expf(-fabsf(pre1)));
    float* xp = xm_ws + b * 2048 + n * Dd;
    float* dp = dl_ws + b * 2048 + n * Dd;
    xp[lr] = xm0;  xp[16 + lr] = xm1;
    dp[lr] = dl0;  dp[16 + lr] = dl1;
    float pp = xm0 * wp0 + xm1 * wp1 + dl0 * wp2 + dl1 * wp3;
    pp += __shfl_xor(pp, 1);
    pp += __shfl_xor(pp, 2);
    pp += __shfl_xor(pp, 4);
    pp += __shfl_xor(pp, 8);
    // after xor-butterfly all 16 lanes hold the sum
    const float ph = 1.f / (1.f + expf(-(pp + bpv)));
    unsigned short* ab = abuf + b * 8192 + n * 64;
    ab[lr]      = f2bf(xm0 * ph);
    ab[16 + lr] = f2bf(xm1 * ph);
    ab[32 + lr] = f2bf(dl0 * ph);
    ab[48 + lr] = f2bf(dl1 * ph);
    if (lr == 0) out_ph[b * 64 + n] = ph;
  }
}

// ---------------------------------------------------------------------------
// Kernel B v5: pairwise intersection volumes.  One block (512 thr) per b.
// j-box held in registers (zero LDS traffic for j); i broadcast from LDS.
// Writes V f32 to d_out and bf16 into abuf[b][4096 + i*64 + j] for kC.
// ---------------------------------------------------------------------------
__global__ __launch_bounds__(512) void kB(
    const float* __restrict__ xm_ws,
    const float* __restrict__ dl_ws,
    float* __restrict__ out_V,              // [256][64][64]
    unsigned short* __restrict__ abuf)      // [256][8192] bf16 (second half)
{
  const int b = blockIdx.x, t = threadIdx.x;
  __shared__ float lo[64][36];
  __shared__ float hi[64][36];

  {
    const int n = t >> 3, dd = (t & 7) * 4;
    float4 x = *(const float4*)(xm_ws + b * 2048 + n * Dd + dd);
    float4 g = *(const float4*)(dl_ws + b * 2048 + n * Dd + dd);
    lo[n][dd + 0] = x.x - g.x;  hi[n][dd + 0] = x.x + g.x;
    lo[n][dd + 1] = x.y - g.y;  hi[n][dd + 1] = x.y + g.y;
    lo[n][dd + 2] = x.z - g.z;  hi[n][dd + 2] = x.z + g.z;
    lo[n][dd + 3] = x.w - g.w;  hi[n][dd + 3] = x.w + g.w;
  }
  __syncthreads();

  const int j  = t & 63;
  const int wv = t >> 6;     // wave id: i-range wv*8 .. wv*8+7

  // own j-box into registers (64 VGPRs)
  float4 lj[8], hj[8];
  #pragma unroll
  for (int q = 0; q < 8; q++) {
    lj[q] = *(const float4*)&lo[j][q * 4];
    hj[q] = *(const float4*)&hi[j][q * 4];
  }
  // rvol_j from (hi-lo)/2: diag stays exactly 1
  float pr = 1.f;
  #pragma unroll
  for (int q = 0; q < 8; q++) {
    pr *= ((hj[q].x - lj[q].x) * 0.5f + EPS);
    pr *= ((hj[q].y - lj[q].y) * 0.5f + EPS);
    pr *= ((hj[q].z - lj[q].z) * 0.5f + EPS);
    pr *= ((hj[q].w - lj[q].w) * 0.5f + EPS);
  }
  const float rv = 1.f / pr;

  #pragma unroll 1
  for (int it = 0; it < 8; it++) {
    const int i = wv * 8 + it;
    float prod = 1.f;
    #pragma unroll
    for (int q = 0; q < 8; q++) {
      const float4 hv = *(const float4*)&hi[i][q * 4];   // broadcast
      const float4 lv = *(const float4*)&lo[i][q * 4];   // broadcast
      float v0 = fmaxf((fminf(hv.x, hj[q].x) - fmaxf(lv.x, lj[q].x)) * 0.5f + EPS, EPS);
      float v1 = fmaxf((fminf(hv.y, hj[q].y) - fmaxf(lv.y, lj[q].y)) * 0.5f + EPS, EPS);
      float v2 = fmaxf((fminf(hv.z, hj[q].z) - fmaxf(lv.z, lj[q].z)) * 0.5f + EPS, EPS);
      float v3 = fmaxf((fminf(hv.w, hj[q].w) - fmaxf(lv.w, lj[q].w)) * 0.5f + EPS, EPS);
      prod *= v0 * v1 * v2 * v3;
    }
    const float V = prod * rv;
    out_V[b * 4096 + i * 64 + j] = V;
    abuf[b * 8192 + 4096 + i * 64 + j] = f2bf(V);
  }
}

// ---------------------------------------------------------------------------
// Kernel C v7 (MFMA split-K): y += [aligned|V] @ [W1;W2]
// grid (Mg=4, s=64) = 256 blocks x 256 thr.  K-step 64 (2 chunks of 64).
// A from abuf (pure bf16 16B copies).  LDS rows padded to 76 shorts (152B):
// all frag reads/stores <=2-way banked.  Epilogue: atomicAdd into out_y.
// ---------------------------------------------------------------------------
__global__ __launch_bounds__(256) void kC(
    const unsigned short* __restrict__ abuf,   // [256][8192] bf16
    const float* __restrict__ W1,      // [4096][100]
    const float* __restrict__ W2,      // [4096][100]
    float* __restrict__ out_y)         // [256][100] accumulate
{
  const int Mg = blockIdx.x;           // 4 row-groups of 64
  const int s  = blockIdx.y;           // 64 K-slices of 128
  const bool isV = (s >= 32);
  const int m0 = (s & 31) * 128;       // offset within half
  const float* __restrict__ W = isV ? W2 : W1;
  const int b0 = Mg * 64;

  __shared__ unsigned short Ab[64][76];    // [row][k] bf16, 152B rows
  __shared__ unsigned short Wb[112][76];   // [col][k] bf16

  const int t = threadIdx.x;
  const int w = t >> 6, l = t & 63;
  const int lr = l & 15, lg = l >> 4;

  f32x4 acc[7] = {};

  // A staging: ar = row (64), ak = 16-k run base (2x16B per thread)
  const int ar = t >> 2, ak = (t & 3) * 16;
  const unsigned short* asrc =
      abuf + (b0 + ar) * 8192 + (isV ? 4096 : 0) + m0 + ak;
  // W staging: wc = col (128 lanes), k-rows wkb + 2i (i 0..31)
  const int wc = t & 127, wkb = t >> 7;

  short8 a0, a1;
  float wv[32];

  auto fetch = [&](int ch) {
    const int kb = ch * 64;
    a0 = *(const short8*)(asrc + kb);
    a1 = *(const short8*)(asrc + kb + 8);
    if (wc < Cc) {
      const float* wp = W + (m0 + kb + wkb) * Cc + wc;
      #pragma unroll
      for (int i = 0; i < 32; i++) wv[i] = wp[2 * i * Cc];
    }
  };

  fetch(0);
  #pragma unroll
  for (int ch = 0; ch < 2; ch++) {
    __syncthreads();   // previous chunk's readers done
    *(short8*)&Ab[ar][ak]     = a0;
    *(short8*)&Ab[ar][ak + 8] = a1;
    if (wc < Cc) {
      #pragma unroll
      for (int i = 0; i < 32; i++) Wb[wc][wkb + 2 * i] = f2bf(wv[i]);
    } else if (wc < 112) {
      #pragma unroll
      for (int i = 0; i < 32; i++) Wb[wc][wkb + 2 * i] = 0;
    }
    __syncthreads();
    if (ch == 0) fetch(1);
    #pragma unroll
    for (int ks = 0; ks < 2; ks++) {
      const int ko = ks * 32 + lg * 8;
      const short8 av = *(const short8*)&Ab[w * 16 + lr][ko];
      #pragma unroll
      for (int nf = 0; nf < 7; nf++) {
        const short8 bv = *(const short8*)&Wb[nf * 16 + lr][ko];
        acc[nf] = __builtin_amdgcn_mfma_f32_16x16x32_bf16(av, bv, acc[nf],
                                                          0, 0, 0);
      }
    }
  }

  // ---- epilogue: atomic accumulate (col=lane&15, row=(lane>>4)*4+q) ----
  #pragma unroll
  for (int nf = 0; nf < 7; nf++) {
    const int col = nf * 16 + lr;
    if (col < Cc) {
      #pragma unroll
      for (int q = 0; q < 4; q++) {
        const int row = b0 + w * 16 + lg * 4 + q;
        atomicAdd(out_y + row * Cc + col, acc[nf][q]);
      }
    }
  }
}

// ---------------------------------------------------------------------------
extern "C" void kernel_launch(void* const* d_in, const int* in_sizes, int n_in,
                              void* d_out, int out_size, void* d_ws, size_t ws_size,
                              hipStream_t stream) {
  const float* h  = (const float*)d_in[0];
  const float* Wc = (const float*)d_in[1];
  const float* bc = (const float*)d_in[2];
  const float* Wo = (const float*)d_in[3];
  const float* bo = (const float*)d_in[4];
  const float* Wp = (const float*)d_in[5];
  const float* bp = (const float*)d_in[6];
  const float* W1 = (const float*)d_in[7];
  const float* b1 = (const float*)d_in[8];
  const float* W2 = (const float*)d_in[9];
  const float* b2 = (const float*)d_in[10];

  float* out    = (float*)d_out;
  float* out_y  = out;                         // [256][100]
  float* out_ph = out + Bb * Cc;               // [256][64]
  float* out_V  = out + Bb * Cc + Bb * Nn;     // [256][64][64]

  float* xm = (float*)d_ws;                        // 524288 f32 (2 MB)
  float* dl = xm + Bb * Nn * Dd;                   // 524288 f32 (2 MB)
  unsigned short* abuf = (unsigned short*)(dl + Bb * Nn * Dd);  // [256][8192] bf16 (4 MB)

  kA<<<dim3(Nn, Bb / 64), 256, 0, stream>>>(h, Wc, bc, Wo, bo, Wp, bp,
                                            b1, b2, xm, dl, abuf, out_ph, out_y);
  kB<<<Bb, 512, 0, stream>>>(xm, dl, out_V, abuf);
  kC<<<dim3(4, 64), 256, 0, stream>>>(abuf, W1, W2, out_y);
}

// Round 12
// 48.299 us; speedup vs baseline: 3.0253x; 1.0070x over previous
//
#include <hip/hip_runtime.h>
#include <hip/hip_bf16.h>
#include <cstdint>

// Problem constants (ConceptBoxModel): B=256, L=512, N=64, D=32, C=100
constexpr int Bb = 256, Ll = 512, Nn = 64, Dd = 32, Cc = 100;
constexpr float EPS = 1e-6f;

typedef __attribute__((ext_vector_type(8))) short short8;   // 8 bf16
typedef __attribute__((ext_vector_type(4))) short short4v;  // 4 bf16
typedef __attribute__((ext_vector_type(4))) float f32x4;    // MFMA C/D frag

__device__ __forceinline__ unsigned short f2bf(float f) {
  union { float f; uint32_t u; } v; v.f = f;
  uint32_t r = v.u + 0x7FFFu + ((v.u >> 16) & 1u);   // RNE
  return (unsigned short)(r >> 16);
}

// ---------------------------------------------------------------------------
// Kernel A v8 (MFMA): x_m = h@Wc + bc ; delta = softplus(h@Wo + bo) ; p_hat
// h-staging packed into 2 x b128 LDS stores (was 16 x u16).
// ---------------------------------------------------------------------------
__global__ __launch_bounds__(256) void kA(
    const float* __restrict__ h,    // [256][512]
    const float* __restrict__ Wc,   // [64][512][32]
    const float* __restrict__ bc,   // [64][32]
    const float* __restrict__ Wo,
    const float* __restrict__ bo,
    const float* __restrict__ Wp,   // [64][64]
    const float* __restrict__ bp,   // [64]
    const float* __restrict__ b1,   // [100]
    const float* __restrict__ b2,   // [100]
    float* __restrict__ xm_ws,      // [256][64][32]
    float* __restrict__ dl_ws,      // [256][64][32]
    unsigned short* __restrict__ abuf,  // [256][8192] bf16 (first half)
    float* __restrict__ out_ph,     // [256][64]
    float* __restrict__ out_y)      // [256][100] (init only)
{
  const int n  = blockIdx.x;
  const int bt = blockIdx.y * 64;
  const int t  = threadIdx.x;
  const int w  = t >> 6, l = t & 63;
  const int lr = l & 15, lg = l >> 4;

  // init y with biases (one block per output row)
  {
    const int bid = blockIdx.x + Nn * blockIdx.y;   // 0..255
    if (t < Cc) out_y[bid * Cc + t] = b1[t] + b2[t];
  }

  __shared__ unsigned short hb[64][72];    // [row][k] bf16, 144B rows
  __shared__ unsigned short wbT[64][72];   // [col][k] bf16, 144B rows

  f32x4 acc[4] = {};   // nf=0,1 -> xm cols ; nf=2,3 -> dl cols

  const int hr = t >> 2,       hc  = (t & 3) * 16;   // h staging
  const int wk = (t >> 3) * 2, wcq = (t & 7) * 4;    // W staging
  const float* hsrc  = h  + (bt + hr) * Ll + hc;
  const float* wcsrc = Wc + n * (Ll * Dd) + wk * Dd + wcq;
  const float* wosrc = Wo + n * (Ll * Dd) + wk * Dd + wcq;

  float4 hp0, hp1, hp2, hp3, c0, c1, o0, o1;
  auto fetch = [&](int k0) {
    const float* hs = hsrc + k0;
    hp0 = *(const float4*)(hs);
    hp1 = *(const float4*)(hs + 4);
    hp2 = *(const float4*)(hs + 8);
    hp3 = *(const float4*)(hs + 12);
    const float* ws = wcsrc + k0 * Dd;
    c0 = *(const float4*)(ws);
    c1 = *(const float4*)(ws + Dd);
    const float* os = wosrc + k0 * Dd;
    o0 = *(const float4*)(os);
    o1 = *(const float4*)(os + Dd);
  };

  fetch(0);
  for (int ch = 0; ch < 8; ch++) {
    __syncthreads();
    {
      // pack 16 bf16 in regs, 2 x b128 stores (row base 144B: 16B-aligned)
      short8 s0, s1;
      s0[0] = (short)f2bf(hp0.x); s0[1] = (short)f2bf(hp0.y);
      s0[2] = (short)f2bf(hp0.z); s0[3] = (short)f2bf(hp0.w);
      s0[4] = (short)f2bf(hp1.x); s0[5] = (short)f2bf(hp1.y);
      s0[6] = (short)f2bf(hp1.z); s0[7] = (short)f2bf(hp1.w);
      s1[0] = (short)f2bf(hp2.x); s1[1] = (short)f2bf(hp2.y);
      s1[2] = (short)f2bf(hp2.z); s1[3] = (short)f2bf(hp2.w);
      s1[4] = (short)f2bf(hp3.x); s1[5] = (short)f2bf(hp3.y);
      s1[6] = (short)f2bf(hp3.z); s1[7] = (short)f2bf(hp3.w);
      *(short8*)&hb[hr][hc]     = s0;
      *(short8*)&hb[hr][hc + 8] = s1;
    }
    {
      const float* c0p = &c0.x; const float* c1p = &c1.x;
      const float* o0p = &o0.x; const float* o1p = &o1.x;
      #pragma unroll
      for (int i = 0; i < 4; i++) {
        unsigned int pc = (unsigned int)f2bf(c0p[i]) |
                          ((unsigned int)f2bf(c1p[i]) << 16);
        *(unsigned int*)&wbT[wcq + i][wk] = pc;
        unsigned int po = (unsigned int)f2bf(o0p[i]) |
                          ((unsigned int)f2bf(o1p[i]) << 16);
        *(unsigned int*)&wbT[32 + wcq + i][wk] = po;
      }
    }
    __syncthreads();
    if (ch < 7) fetch((ch + 1) * 64);
    const int arow = w * 16 + lr;
    #pragma unroll
    for (int ks = 0; ks < 2; ks++) {
      const int ko = ks * 32 + lg * 8;
      const short8 av = *(const short8*)&hb[arow][ko];
      #pragma unroll
      for (int nf = 0; nf < 4; nf++) {
        const short8 bv = *(const short8*)&wbT[nf * 16 + lr][ko];
        acc[nf] = __builtin_amdgcn_mfma_f32_16x16x32_bf16(av, bv, acc[nf],
                                                          0, 0, 0);
      }
    }
  }

  const float bc0 = bc[n * Dd + lr],      bc1 = bc[n * Dd + 16 + lr];
  const float bo0 = bo[n * Dd + lr],      bo1 = bo[n * Dd + 16 + lr];
  const float wp0 = Wp[n * 64 + lr],      wp1 = Wp[n * 64 + 16 + lr];
  const float wp2 = Wp[n * 64 + 32 + lr], wp3 = Wp[n * 64 + 48 + lr];
  const float bpv = bp[n];

  #pragma unroll
  for (int q = 0; q < 4; q++) {
    const int b = bt + w * 16 + lg * 4 + q;
    const float xm0  = acc[0][q] + bc0;
    const float xm1  = acc[1][q] + bc1;
    const float pre0 = acc[2][q] + bo0;
    const float pre1 = acc[3][q] + bo1;
    // stable softplus = max(x,0) + log1p(exp(-|x|))
    const float dl0 = fmaxf(pre0, 0.f) + log1pf(expf(-fabsf(pre0)));
    const float dl1 = fmaxf(pre1, 0.f) + log1pf(expf(-fabsf(pre1)));
    float* xp = xm_ws + b * 2048 + n * Dd;
    float* dp = dl_ws + b * 2048 + n * Dd;
    xp[lr] = xm0;  xp[16 + lr] = xm1;
    dp[lr] = dl0;  dp[16 + lr] = dl1;
    float pp = xm0 * wp0 + xm1 * wp1 + dl0 * wp2 + dl1 * wp3;
    pp += __shfl_xor(pp, 1);
    pp += __shfl_xor(pp, 2);
    pp += __shfl_xor(pp, 4);
    pp += __shfl_xor(pp, 8);
    // after xor-butterfly all 16 lanes hold the sum
    const float ph = 1.f / (1.f + expf(-(pp + bpv)));
    unsigned short* ab = abuf + b * 8192 + n * 64;
    ab[lr]      = f2bf(xm0 * ph);
    ab[16 + lr] = f2bf(xm1 * ph);
    ab[32 + lr] = f2bf(dl0 * ph);
    ab[48 + lr] = f2bf(dl1 * ph);
    if (lr == 0) out_ph[b * 64 + n] = ph;
  }
}

// ---------------------------------------------------------------------------
// Kernel B v5: pairwise intersection volumes.  One block (512 thr) per b.
// j-box in registers; i broadcast from LDS.  V -> d_out f32 + abuf bf16.
// ---------------------------------------------------------------------------
__global__ __launch_bounds__(512) void kB(
    const float* __restrict__ xm_ws,
    const float* __restrict__ dl_ws,
    float* __restrict__ out_V,              // [256][64][64]
    unsigned short* __restrict__ abuf)      // [256][8192] bf16 (second half)
{
  const int b = blockIdx.x, t = threadIdx.x;
  __shared__ float lo[64][36];
  __shared__ float hi[64][36];

  {
    const int n = t >> 3, dd = (t & 7) * 4;
    float4 x = *(const float4*)(xm_ws + b * 2048 + n * Dd + dd);
    float4 g = *(const float4*)(dl_ws + b * 2048 + n * Dd + dd);
    lo[n][dd + 0] = x.x - g.x;  hi[n][dd + 0] = x.x + g.x;
    lo[n][dd + 1] = x.y - g.y;  hi[n][dd + 1] = x.y + g.y;
    lo[n][dd + 2] = x.z - g.z;  hi[n][dd + 2] = x.z + g.z;
    lo[n][dd + 3] = x.w - g.w;  hi[n][dd + 3] = x.w + g.w;
  }
  __syncthreads();

  const int j  = t & 63;
  const int wv = t >> 6;     // wave id: i-range wv*8 .. wv*8+7

  float4 lj[8], hj[8];
  #pragma unroll
  for (int q = 0; q < 8; q++) {
    lj[q] = *(const float4*)&lo[j][q * 4];
    hj[q] = *(const float4*)&hi[j][q * 4];
  }
  float pr = 1.f;
  #pragma unroll
  for (int q = 0; q < 8; q++) {
    pr *= ((hj[q].x - lj[q].x) * 0.5f + EPS);
    pr *= ((hj[q].y - lj[q].y) * 0.5f + EPS);
    pr *= ((hj[q].z - lj[q].z) * 0.5f + EPS);
    pr *= ((hj[q].w - lj[q].w) * 0.5f + EPS);
  }
  const float rv = 1.f / pr;

  #pragma unroll 1
  for (int it = 0; it < 8; it++) {
    const int i = wv * 8 + it;
    float prod = 1.f;
    #pragma unroll
    for (int q = 0; q < 8; q++) {
      const float4 hv = *(const float4*)&hi[i][q * 4];   // broadcast
      const float4 lv = *(const float4*)&lo[i][q * 4];   // broadcast
      float v0 = fmaxf((fminf(hv.x, hj[q].x) - fmaxf(lv.x, lj[q].x)) * 0.5f + EPS, EPS);
      float v1 = fmaxf((fminf(hv.y, hj[q].y) - fmaxf(lv.y, lj[q].y)) * 0.5f + EPS, EPS);
      float v2 = fmaxf((fminf(hv.z, hj[q].z) - fmaxf(lv.z, lj[q].z)) * 0.5f + EPS, EPS);
      float v3 = fmaxf((fminf(hv.w, hj[q].w) - fmaxf(lv.w, lj[q].w)) * 0.5f + EPS, EPS);
      prod *= v0 * v1 * v2 * v3;
    }
    const float V = prod * rv;
    out_V[b * 4096 + i * 64 + j] = V;
    abuf[b * 8192 + 4096 + i * 64 + j] = f2bf(V);
  }
}

// ---------------------------------------------------------------------------
// Kernel C v8 (MFMA split-K): y += [aligned|V] @ [W1;W2]
// grid (Mg=4, s=64) x 256 thr.  W staging: (col, half) map, 32 consecutive
// k per thread -> 8 x b64 LDS stores (was 32 x u16).  Identity k-order.
// ---------------------------------------------------------------------------
__global__ __launch_bounds__(256) void kC(
    const unsigned short* __restrict__ abuf,   // [256][8192] bf16
    const float* __restrict__ W1,      // [4096][100]
    const float* __restrict__ W2,      // [4096][100]
    float* __restrict__ out_y)         // [256][100] accumulate
{
  const int Mg = blockIdx.x;           // 4 row-groups of 64
  const int s  = blockIdx.y;           // 64 K-slices of 128
  const bool isV = (s >= 32);
  const int m0 = (s & 31) * 128;       // offset within half
  const float* __restrict__ W = isV ? W2 : W1;
  const int b0 = Mg * 64;

  __shared__ unsigned short Ab[64][76];    // [row][k] bf16, 152B rows
  __shared__ unsigned short Wb[112][76];   // [col][k] bf16

  const int t = threadIdx.x;
  const int w = t >> 6, l = t & 63;
  const int lr = l & 15, lg = l >> 4;

  f32x4 acc[7] = {};

  // A staging: ar = row (64), ak = 16-k run base (2x16B per thread)
  const int ar = t >> 2, ak = (t & 3) * 16;
  const unsigned short* asrc =
      abuf + (b0 + ar) * 8192 + (isV ? 4096 : 0) + m0 + ak;
  // W staging: wc = col (128 lanes), half = k-half (32 consecutive k each)
  const int wc = t & 127, half = t >> 7;

  short8 a0, a1;
  float wv[32];

  auto fetch = [&](int ch) {
    const int kb = ch * 64;
    a0 = *(const short8*)(asrc + kb);
    a1 = *(const short8*)(asrc + kb + 8);
    if (wc < Cc) {
      const float* wp = W + (m0 + kb + half * 32) * Cc + wc;
      #pragma unroll
      for (int i = 0; i < 32; i++) wv[i] = wp[i * Cc];
    }
  };

  fetch(0);
  #pragma unroll
  for (int ch = 0; ch < 2; ch++) {
    __syncthreads();   // previous chunk's readers done
    *(short8*)&Ab[ar][ak]     = a0;
    *(short8*)&Ab[ar][ak + 8] = a1;
    if (wc < 112) {
      #pragma unroll
      for (int q8 = 0; q8 < 8; q8++) {
        short4v pk;
        if (wc < Cc) {
          pk[0] = (short)f2bf(wv[q8 * 4 + 0]);
          pk[1] = (short)f2bf(wv[q8 * 4 + 1]);
          pk[2] = (short)f2bf(wv[q8 * 4 + 2]);
          pk[3] = (short)f2bf(wv[q8 * 4 + 3]);
        } else {
          pk[0] = 0; pk[1] = 0; pk[2] = 0; pk[3] = 0;
        }
        *(short4v*)&Wb[wc][half * 32 + q8 * 4] = pk;   // 8B-aligned b64
      }
    }
    __syncthreads();
    if (ch == 0) fetch(1);
    #pragma unroll
    for (int ks = 0; ks < 2; ks++) {
      const int ko = ks * 32 + lg * 8;
      const short8 av = *(const short8*)&Ab[w * 16 + lr][ko];
      #pragma unroll
      for (int nf = 0; nf < 7; nf++) {
        const short8 bv = *(const short8*)&Wb[nf * 16 + lr][ko];
        acc[nf] = __builtin_amdgcn_mfma_f32_16x16x32_bf16(av, bv, acc[nf],
                                                          0, 0, 0);
      }
    }
  }

  // ---- epilogue: atomic accumulate (col=lane&15, row=(lane>>4)*4+q) ----
  #pragma unroll
  for (int nf = 0; nf < 7; nf++) {
    const int col = nf * 16 + lr;
    if (col < Cc) {
      #pragma unroll
      for (int q = 0; q < 4; q++) {
        const int row = b0 + w * 16 + lg * 4 + q;
        atomicAdd(out_y + row * Cc + col, acc[nf][q]);
      }
    }
  }
}

// ---------------------------------------------------------------------------
extern "C" void kernel_launch(void* const* d_in, const int* in_sizes, int n_in,
                              void* d_out, int out_size, void* d_ws, size_t ws_size,
                              hipStream_t stream) {
  const float* h  = (const float*)d_in[0];
  const float* Wc = (const float*)d_in[1];
  const float* bc = (const float*)d_in[2];
  const float* Wo = (const float*)d_in[3];
  const float* bo = (const float*)d_in[4];
  const float* Wp = (const float*)d_in[5];
  const float* bp = (const float*)d_in[6];
  const float* W1 = (const float*)d_in[7];
  const float* b1 = (const float*)d_in[8];
  const float* W2 = (const float*)d_in[9];
  const float* b2 = (const float*)d_in[10];

  float* out    = (float*)d_out;
  float* out_y  = out;                         // [256][100]
  float* out_ph = out + Bb * Cc;               // [256][64]
  float* out_V  = out + Bb * Cc + Bb * Nn;     // [256][64][64]

  float* xm = (float*)d_ws;                        // 524288 f32 (2 MB)
  float* dl = xm + Bb * Nn * Dd;                   // 524288 f32 (2 MB)
  unsigned short* abuf = (unsigned short*)(dl + Bb * Nn * Dd);  // 4 MB bf16

  kA<<<dim3(Nn, Bb / 64), 256, 0, stream>>>(h, Wc, bc, Wo, bo, Wp, bp,
                                            b1, b2, xm, dl, abuf, out_ph, out_y);
  kB<<<Bb, 512, 0, stream>>>(xm, dl, out_V, abuf);
  kC<<<dim3(4, 64), 256, 0, stream>>>(abuf, W1, W2, out_y);
}